// Round 4
// baseline (25867.856 us; speedup 1.0000x reference)
//
#include <hip/hip_runtime.h>
#include <math.h>

#define BATCH 512
#define SEQ_T 128
#define NIN   500
#define NINP  512          // padded K for x / w_ih0 planes
#define HID   1024
#define G3    3072
#define HPS1  (512*1024)   // plane stride for [3][512][1024] h buffers

typedef short  short8 __attribute__((ext_vector_type(8)));
typedef float  f32x4  __attribute__((ext_vector_type(4)));
typedef unsigned short u16;
typedef u16 u16x8 __attribute__((ext_vector_type(8)));

// ---------------------------------------------------------------------------
// fp32 -> 3-way bf16 truncation split: f ~= h + m + l, residual ~2^-24 |f|
// ---------------------------------------------------------------------------
__device__ __forceinline__ void split3(float f, u16 &h, u16 &m, u16 &l) {
    unsigned u = __float_as_uint(f);
    h = (u16)(u >> 16);
    float fh = __uint_as_float(u & 0xFFFF0000u);
    float r1 = f - fh;
    unsigned u1 = __float_as_uint(r1);
    m = (u16)(u1 >> 16);
    float fm = __uint_as_float(u1 & 0xFFFF0000u);
    float r2 = r1 - fm;
    l = (u16)(__float_as_uint(r2) >> 16);
}

__device__ __forceinline__ float b2f(u16 v) {
    return __uint_as_float((unsigned)v << 16);
}

// ---------------------------------------------------------------------------
// Generic fp32 [R][sC] -> bf16 planes [3][R][dC], zero-padding cols sC..dC.
// sC, dC multiples of 4. grid = R*dC/4/256.
// ---------------------------------------------------------------------------
__global__ __launch_bounds__(256) void split_mat(
    const float* __restrict__ src, u16* __restrict__ dst,
    int R, int sC, int dC)
{
    long idx = (long)blockIdx.x * 256 + threadIdx.x;
    int cpr = dC >> 2;
    long total = (long)R * cpr;
    if (idx >= total) return;
    int c4 = (int)(idx % cpr) << 2;
    long r = idx / cpr;
    float4 v = make_float4(0.f, 0.f, 0.f, 0.f);
    if (c4 < sC) v = *(const float4*)(src + r * sC + c4);
    u16 h0,m0,l0,h1,m1,l1,h2,m2,l2,h3,m3,l3;
    split3(v.x, h0, m0, l0);
    split3(v.y, h1, m1, l1);
    split3(v.z, h2, m2, l2);
    split3(v.w, h3, m3, l3);
    long PS = (long)R * dC;
    long o  = r * dC + c4;
    u16* dh = dst + o; dh[0]=h0; dh[1]=h1; dh[2]=h2; dh[3]=h3;
    u16* dm = dst + PS + o; dm[0]=m0; dm[1]=m1; dm[2]=m2; dm[3]=m3;
    u16* dl = dst + 2*PS + o; dl[0]=l0; dl[1]=l1; dl[2]=l2; dl[3]=l3;
}

// ---------------------------------------------------------------------------
// x [B][T][NIN] chunk (t0..t0+Tc) -> reordered planes [3][Tc*512][512]
// row r = tt*512 + b; cols padded 500->512.
// ---------------------------------------------------------------------------
__global__ __launch_bounds__(256) void split_x(
    const float* __restrict__ x, u16* __restrict__ dst, int t0, int Tc)
{
    long idx = (long)blockIdx.x * 256 + threadIdx.x;   // Tc*512*128
    if (idx >= (long)Tc * 512 * 128) return;
    int c4 = (int)(idx & 127) << 2;
    long rr = idx >> 7;
    int tt = (int)(rr >> 9), b = (int)(rr & 511);
    float4 v = make_float4(0.f, 0.f, 0.f, 0.f);
    if (c4 < NIN) v = *(const float4*)(x + ((long)b * SEQ_T + t0 + tt) * NIN + c4);
    u16 h0,m0,l0,h1,m1,l1,h2,m2,l2,h3,m3,l3;
    split3(v.x, h0, m0, l0);
    split3(v.y, h1, m1, l1);
    split3(v.z, h2, m2, l2);
    split3(v.w, h3, m3, l3);
    long PS = (long)Tc * 512 * NINP;
    long o  = rr * NINP + c4;
    u16* dh = dst + o; dh[0]=h0; dh[1]=h1; dh[2]=h2; dh[3]=h3;
    u16* dm = dst + PS + o; dm[0]=m0; dm[1]=m1; dm[2]=m2; dm[3]=m3;
    u16* dl = dst + 2*PS + o; dl[0]=l0; dl[1]=l1; dl[2]=l2; dl[3]=l3;
}

// ---------------------------------------------------------------------------
// Plane GEMM: C[M,NN] = A[M,K] @ W[NN,K]^T + bias; A,W are bf16 h/m/l planes.
// 6-product fp32-grade accumulate. M%64==0, K%32==0. grid (M/64, ceil(NN/64)).
// 256 thr = 4 waves; wave tile 32x32 (2x2 of v_mfma_f32_16x16x32_bf16).
// ---------------------------------------------------------------------------
__global__ __launch_bounds__(256) void gemm_ps(
    const u16* __restrict__ Ap, long aPS, int lda,
    const u16* __restrict__ Wp, long wPS, int ldb,
    const float* __restrict__ bias,
    float* __restrict__ C, int ldc,
    int M, int NN, int K)
{
    __shared__ __align__(16) u16 As[3][4][64][8];
    __shared__ __align__(16) u16 Bs[3][4][64][8];
    const int tid  = threadIdx.x;
    const int lane = tid & 63;
    const int wave = tid >> 6;
    const int wm = wave & 1, wn = wave >> 1;
    const int q = lane >> 4, l16 = lane & 15;
    const int bm = blockIdx.x * 64, bn = blockIdx.y * 64;

    f32x4 acc[2][2] = {};
    const int PA[6] = {0,0,1,1,0,2}, PB[6] = {0,1,0,1,2,0};

    for (int k0 = 0; k0 < K; k0 += 32) {
        #pragma unroll
        for (int s = 0; s < 6; s++) {
            int c = tid + 256 * s;
            if (c < 768) {
                int row = c & 63, kq = (c >> 6) & 3, p = c >> 8;
                u16x8 v = *(const u16x8*)(Ap + (long)p * aPS + (long)(bm + row) * lda + k0 + kq * 8);
                *(u16x8*)&As[p][kq][row][0] = v;
            } else {
                int cc = c - 768;
                int row = cc & 63, kq = (cc >> 6) & 3, p = cc >> 8;
                int gn = bn + row;
                u16x8 v = {0,0,0,0,0,0,0,0};
                if (gn < NN) v = *(const u16x8*)(Wp + (long)p * wPS + (long)gn * ldb + k0 + kq * 8);
                *(u16x8*)&Bs[p][kq][row][0] = v;
            }
        }
        __syncthreads();
        short8 af[3][2], bf[3][2];
        #pragma unroll
        for (int p = 0; p < 3; p++)
            #pragma unroll
            for (int t = 0; t < 2; t++) {
                af[p][t] = *(const short8*)&As[p][q][wm*32 + t*16 + l16][0];
                bf[p][t] = *(const short8*)&Bs[p][q][wn*32 + t*16 + l16][0];
            }
        #pragma unroll
        for (int pr = 0; pr < 6; pr++)
            #pragma unroll
            for (int ti = 0; ti < 2; ti++)
                #pragma unroll
                for (int tj = 0; tj < 2; tj++)
                    acc[ti][tj] = __builtin_amdgcn_mfma_f32_16x16x32_bf16(
                        af[PA[pr]][ti], bf[PB[pr]][tj], acc[ti][tj], 0, 0, 0);
        __syncthreads();
    }
    #pragma unroll
    for (int ti = 0; ti < 2; ti++)
    #pragma unroll
    for (int tj = 0; tj < 2; tj++) {
        int gn = bn + wn*32 + tj*16 + l16;
        if (gn >= NN) continue;
        float bv = bias[gn];
        #pragma unroll
        for (int r = 0; r < 4; r++) {
            int gm = bm + wm*32 + ti*16 + q*4 + r;
            C[(long)gm * ldc + gn] = acc[ti][tj][r] + bv;
        }
    }
}

// ---------------------------------------------------------------------------
// Fused 3-gate recurrent GEMM + GRU update.
// gh[:, 3 gates] = h_prev @ W_hh^T (+b_hh in epilogue); then GRU update with
// gx slab; h_next written as bf16 h/m/l planes.
// grid (512/64=8, 1024/32=32) = 256 blocks; 256 thr = 4 waves =
// 2 m-halves x 2-way K-split; wave tile 32 rows x 32 cols x 3 gates.
// LDS 60 KB staging (2 k-segs), reused for cross-wave reduction.
// ---------------------------------------------------------------------------
__global__ __launch_bounds__(256, 1) void gru_fused(
    const u16* __restrict__ Hp, long hpPS,
    const u16* __restrict__ Wp,           // [3][3072][1024]
    const float* __restrict__ bhh,        // [3072]
    const float* __restrict__ gx,         // [512][3072] slab (incl b_ih)
    u16* __restrict__ Hn, long hnPS)
{
    __shared__ __align__(16) char smem[61440];
    u16* Asm = (u16*)smem;                 // [seg2][p3][kq4][row64][8] = 24576 B
    u16* Bsm = (u16*)(smem + 24576);       // [seg2][g3][p3][kq4][row32][8] = 36864 B
    const int tid  = threadIdx.x;
    const int lane = tid & 63;
    const int w    = tid >> 6;
    const int seg  = w >> 1;               // k-segment of this wave
    const int mh   = w & 1;                // m-half of this wave
    const int q = lane >> 4, l16 = lane & 15;
    const int bm = blockIdx.x * 64, bn = blockIdx.y * 32;
    const long WPS = 3072L * 1024;

    f32x4 acc[3][2][2] = {};               // [gate][mt][nt]
    const int PA[6] = {0,0,1,1,0,2}, PB[6] = {0,1,0,1,2,0};

    for (int it = 0; it < 16; it++) {
        int k0 = it * 32;
        #pragma unroll
        for (int s = 0; s < 15; s++) {
            int c = tid + 256 * s;         // 0..3839
            if (c < 1536) {                // A: 2 seg x 3 p x 4 kq x 64 row
                int sg = (c >= 768) ? 1 : 0;
                int r  = c - sg * 768;
                int row = r & 63, kq = (r >> 6) & 3, p = r >> 8;
                int k = sg * 512 + k0 + kq * 8;
                u16x8 v = *(const u16x8*)(Hp + (long)p * hpPS + (long)(bm + row) * HID + k);
                *(u16x8*)(Asm + (((sg*3 + p)*4 + kq)*64 + row)*8) = v;
            } else {                       // B: 2 seg x 9 gp x 4 kq x 32 row
                int d  = c - 1536;         // 0..2303
                int sg = (d >= 1152) ? 1 : 0;
                int r  = d - sg * 1152;
                int row = r & 31, kq = (r >> 5) & 3, gp = r >> 7;   // gp 0..8
                int g = (gp >= 6) ? 2 : (gp >= 3) ? 1 : 0;
                int p = gp - 3 * g;
                int k = sg * 512 + k0 + kq * 8;
                u16x8 v = *(const u16x8*)(Wp + (long)p * WPS + (long)(g*HID + bn + row) * HID + k);
                *(u16x8*)(Bsm + ((((sg*3 + g)*3 + p)*4 + kq)*32 + row)*8) = v;
            }
        }
        __syncthreads();
        short8 af[3][2];
        #pragma unroll
        for (int p = 0; p < 3; p++)
            #pragma unroll
            for (int mt = 0; mt < 2; mt++)
                af[p][mt] = *(const short8*)(Asm + (((seg*3 + p)*4 + q)*64 + mh*32 + mt*16 + l16)*8);
        #pragma unroll
        for (int g = 0; g < 3; g++) {
            short8 bf[3][2];
            #pragma unroll
            for (int p = 0; p < 3; p++)
                #pragma unroll
                for (int nt = 0; nt < 2; nt++)
                    bf[p][nt] = *(const short8*)(Bsm + ((((seg*3 + g)*3 + p)*4 + q)*32 + nt*16 + l16)*8);
            #pragma unroll
            for (int pr = 0; pr < 6; pr++)
                #pragma unroll
                for (int mt = 0; mt < 2; mt++)
                    #pragma unroll
                    for (int nt = 0; nt < 2; nt++)
                        acc[g][mt][nt] = __builtin_amdgcn_mfma_f32_16x16x32_bf16(
                            af[PA[pr]][mt], bf[PB[pr]][nt], acc[g][mt][nt], 0, 0, 0);
        }
        __syncthreads();
    }

    // ---- cross-wave k-split reduction (reuse LDS) ----
    float* red = (float*)smem;             // [w4][lane64][48]
    int base = (w * 64 + lane) * 48;
    #pragma unroll
    for (int g = 0; g < 3; g++)
    #pragma unroll
    for (int mt = 0; mt < 2; mt++)
    #pragma unroll
    for (int nt = 0; nt < 2; nt++)
    #pragma unroll
    for (int r = 0; r < 4; r++)
        red[base + ((g*2 + mt)*2 + nt)*4 + r] = acc[g][mt][nt][r];
    __syncthreads();

    // ---- fused GRU update epilogue: 8 positions per thread ----
    #pragma unroll
    for (int pp = 0; pp < 8; pp++) {
        int pos = tid * 8 + pp;            // 0..2047 over 64 rows x 32 cols
        int row = pos >> 5, col = pos & 31;
        int mh2 = row >> 5, mt = (row >> 4) & 1, qq = (row >> 2) & 3, rr = row & 3;
        int nt = col >> 4, ll = col & 15;
        int lane2 = qq * 16 + ll;
        float S[3];
        #pragma unroll
        for (int g = 0; g < 3; g++) {
            int slot = ((g*2 + mt)*2 + nt)*4 + rr;
            S[g] = red[((0*2 + mh2) * 64 + lane2) * 48 + slot]
                 + red[((1*2 + mh2) * 64 + lane2) * 48 + slot];
        }
        int gm = bm + row, gc = bn + col;
        const float* gxr = gx + (long)gm * G3;
        float xr = gxr[gc], xz = gxr[HID + gc], xn = gxr[2*HID + gc];
        float hr = S[0] + bhh[gc];
        float hz = S[1] + bhh[HID + gc];
        float hn = S[2] + bhh[2*HID + gc];
        float rg = 1.f / (1.f + expf(-(xr + hr)));
        float zg = 1.f / (1.f + expf(-(xz + hz)));
        float ng = tanhf(xn + rg * hn);
        long ho = (long)gm * HID + gc;
        float hp = b2f(Hp[ho]) + b2f(Hp[hpPS + ho]) + b2f(Hp[2*hpPS + ho]);
        float hv = (1.f - zg) * ng + zg * hp;
        u16 sh, sm2, sl; split3(hv, sh, sm2, sl);
        Hn[ho] = sh; Hn[hnPS + ho] = sm2; Hn[2*hnPS + ho] = sl;
    }
}

// ===========================================================================
// Legacy (round-3) kernels — fallback when workspace is too small for planes
// ===========================================================================
__global__ __launch_bounds__(256) void gemm_b6(
    const float* __restrict__ A, long a_stride_t, long a_stride_b,
    const float* __restrict__ W,
    const float* __restrict__ bias,
    float* __restrict__ C,
    int M, int NN, int K)
{
    __shared__ __align__(16) short Ah[4][64][8], Am[4][64][8], Al[4][64][8];
    __shared__ __align__(16) short Bh[4][64][8], Bm[4][64][8], Bl[4][64][8];
    const int tid  = threadIdx.x;
    const int lane = tid & 63;
    const int wave = tid >> 6;
    const int bm   = blockIdx.x * 64;
    const int bn   = blockIdx.y * 64;
    const int mrow = (wave & 1) * 32;
    const int ncol = (wave >> 1) * 32;
    const int q    = lane >> 4;
    const int l16  = lane & 15;
    const int arow = tid >> 2;
    const int c0   = tid & 3;
    const long aoff = (long)((bm + arow) >> 9) * a_stride_t
                    + (long)((bm + arow) & 511) * a_stride_b;
    const int  gnW  = bn + arow;
    const long woff = (long)gnW * (long)K;
    const bool wvalid = (gnW < NN);

    f32x4 accP[4] = {};
    f32x4 accQ[4] = {};

    for (int k0 = 0; k0 < K; k0 += 32) {
        const bool full = (k0 + 32 <= K);
        #pragma unroll
        for (int cc = 0; cc < 2; cc++) {
            int c  = c0 + 4 * cc;
            int kk = k0 + 4 * c;
            float fa[4], fw[4];
            if (full) {
                float4 va = *(const float4*)(A + aoff + kk);
                fa[0] = va.x; fa[1] = va.y; fa[2] = va.z; fa[3] = va.w;
                if (wvalid) {
                    float4 vw = *(const float4*)(W + woff + kk);
                    fw[0] = vw.x; fw[1] = vw.y; fw[2] = vw.z; fw[3] = vw.w;
                } else { fw[0] = fw[1] = fw[2] = fw[3] = 0.f; }
            } else {
                #pragma unroll
                for (int j = 0; j < 4; j++) {
                    int gk = kk + j;
                    fa[j] = (gk < K) ? A[aoff + gk] : 0.f;
                    fw[j] = (wvalid && gk < K) ? W[woff + gk] : 0.f;
                }
            }
            u16 t0,t1,t2;
            short4 ha, ma, la, hb, mb, lb;
            split3(fa[0], t0,t1,t2); ha.x=(short)t0; ma.x=(short)t1; la.x=(short)t2;
            split3(fa[1], t0,t1,t2); ha.y=(short)t0; ma.y=(short)t1; la.y=(short)t2;
            split3(fa[2], t0,t1,t2); ha.z=(short)t0; ma.z=(short)t1; la.z=(short)t2;
            split3(fa[3], t0,t1,t2); ha.w=(short)t0; ma.w=(short)t1; la.w=(short)t2;
            split3(fw[0], t0,t1,t2); hb.x=(short)t0; mb.x=(short)t1; lb.x=(short)t2;
            split3(fw[1], t0,t1,t2); hb.y=(short)t0; mb.y=(short)t1; lb.y=(short)t2;
            split3(fw[2], t0,t1,t2); hb.z=(short)t0; mb.z=(short)t1; lb.z=(short)t2;
            split3(fw[3], t0,t1,t2); hb.w=(short)t0; mb.w=(short)t1; lb.w=(short)t2;
            int kq = c >> 1, ko = (c & 1) * 4;
            *(short4*)&Ah[kq][arow][ko] = ha;
            *(short4*)&Am[kq][arow][ko] = ma;
            *(short4*)&Al[kq][arow][ko] = la;
            *(short4*)&Bh[kq][arow][ko] = hb;
            *(short4*)&Bm[kq][arow][ko] = mb;
            *(short4*)&Bl[kq][arow][ko] = lb;
        }
        __syncthreads();
        short8 a_h[2], a_m[2], a_l[2], b_h[2], b_m[2], b_l[2];
        #pragma unroll
        for (int ti = 0; ti < 2; ti++) {
            int r = mrow + ti * 16 + l16;
            a_h[ti] = *(const short8*)Ah[q][r];
            a_m[ti] = *(const short8*)Am[q][r];
            a_l[ti] = *(const short8*)Al[q][r];
            int n = ncol + ti * 16 + l16;
            b_h[ti] = *(const short8*)Bh[q][n];
            b_m[ti] = *(const short8*)Bm[q][n];
            b_l[ti] = *(const short8*)Bl[q][n];
        }
        #pragma unroll
        for (int ti = 0; ti < 2; ti++)
        #pragma unroll
        for (int tj = 0; tj < 2; tj++) {
            int t = ti * 2 + tj;
            accP[t] = __builtin_amdgcn_mfma_f32_16x16x32_bf16(a_h[ti], b_h[tj], accP[t], 0, 0, 0);
            accP[t] = __builtin_amdgcn_mfma_f32_16x16x32_bf16(a_m[ti], b_h[tj], accP[t], 0, 0, 0);
            accP[t] = __builtin_amdgcn_mfma_f32_16x16x32_bf16(a_l[ti], b_h[tj], accP[t], 0, 0, 0);
            accQ[t] = __builtin_amdgcn_mfma_f32_16x16x32_bf16(a_h[ti], b_m[tj], accQ[t], 0, 0, 0);
            accQ[t] = __builtin_amdgcn_mfma_f32_16x16x32_bf16(a_m[ti], b_m[tj], accQ[t], 0, 0, 0);
            accQ[t] = __builtin_amdgcn_mfma_f32_16x16x32_bf16(a_h[ti], b_l[tj], accQ[t], 0, 0, 0);
        }
        __syncthreads();
    }
    #pragma unroll
    for (int ti = 0; ti < 2; ti++)
    #pragma unroll
    for (int tj = 0; tj < 2; tj++) {
        int t = ti * 2 + tj;
        f32x4 s = accP[t] + accQ[t];
        int gn = bn + ncol + tj * 16 + l16;
        if (gn < NN) {
            float bv = bias[gn];
            #pragma unroll
            for (int r = 0; r < 4; r++) {
                int gm = bm + mrow + ti * 16 + q * 4 + r;
                C[(long)gm * NN + gn] = s[r] + bv;
            }
        }
    }
}

__global__ __launch_bounds__(256) void gru_update4(
    const float4* __restrict__ gx,
    const float4* __restrict__ gh,
    const float4* __restrict__ hprev,
    float4* __restrict__ hnew)
{
    int idx = blockIdx.x * 256 + threadIdx.x;
    int b   = idx >> 8;
    int h4  = idx & 255;
    const float4* gxr = gx + (long)b * (G3 / 4);
    const float4* ghr = gh + (long)b * (G3 / 4);
    float4 xr = gxr[h4], xz = gxr[256 + h4], xn = gxr[512 + h4];
    float4 hr = ghr[h4], hz = ghr[256 + h4], hn = ghr[512 + h4];
    float4 hp = hprev[idx];
    float4 o;
#define GRUC(c) { \
    float r_ = 1.f / (1.f + expf(-(xr.c + hr.c))); \
    float z_ = 1.f / (1.f + expf(-(xz.c + hz.c))); \
    float n_ = tanhf(xn.c + r_ * hn.c); \
    o.c = (1.f - z_) * n_ + z_ * hp.c; }
    GRUC(x) GRUC(y) GRUC(z) GRUC(w)
#undef GRUC
    hnew[idx] = o;
}

// ---------------------------------------------------------------------------
// block reductions (256 threads = 4 waves of 64)
// ---------------------------------------------------------------------------
__device__ __forceinline__ float block_reduce_sum(float v) {
    __shared__ float red[4];
    #pragma unroll
    for (int o = 32; o > 0; o >>= 1) v += __shfl_down(v, o);
    __syncthreads();
    if ((threadIdx.x & 63) == 0) red[threadIdx.x >> 6] = v;
    __syncthreads();
    return red[0] + red[1] + red[2] + red[3];
}

__device__ __forceinline__ float block_reduce_max(float v) {
    __shared__ float red[4];
    #pragma unroll
    for (int o = 32; o > 0; o >>= 1) v = fmaxf(v, __shfl_down(v, o));
    __syncthreads();
    if ((threadIdx.x & 63) == 0) red[threadIdx.x >> 6] = v;
    __syncthreads();
    return fmaxf(fmaxf(red[0], red[1]), fmaxf(red[2], red[3]));
}

// ---------------------------------------------------------------------------
__global__ __launch_bounds__(256) void ln_silu(
    float* __restrict__ z,
    const float* __restrict__ gamma,
    const float* __restrict__ beta)
{
    int b = blockIdx.x;
    float* row = z + (long)b * HID;
    float v[4];
    float s = 0.f;
    #pragma unroll
    for (int i = 0; i < 4; i++) { v[i] = row[threadIdx.x + 256 * i]; s += v[i]; }
    float mean = block_reduce_sum(s) * (1.f / HID);
    float vs = 0.f;
    #pragma unroll
    for (int i = 0; i < 4; i++) { float d = v[i] - mean; vs += d * d; }
    float var = block_reduce_sum(vs) * (1.f / HID);
    float inv = 1.f / sqrtf(var + 1e-5f);
    #pragma unroll
    for (int i = 0; i < 4; i++) {
        int col = threadIdx.x + 256 * i;
        float zz = (v[i] - mean) * inv * gamma[col] + beta[col];
        row[col] = zz / (1.f + expf(-zz));
    }
}

// ---------------------------------------------------------------------------
__global__ __launch_bounds__(256) void head_softmax_rebalance(
    const float* __restrict__ scores,
    float* __restrict__ out)
{
    int b = blockIdx.x;
    const float* srow = scores + (long)b * NIN;
    int i0 = threadIdx.x;
    int i1 = threadIdx.x + 256;
    bool v1 = (i1 < NIN);

    float s0 = srow[i0];
    if (s0 < 0.f) s0 = -INFINITY;
    float s1 = v1 ? srow[i1] : -INFINITY;
    if (s1 < 0.f) s1 = -INFINITY;

    float m  = block_reduce_max(fmaxf(s0, s1));
    float e0 = expf(s0 - m);
    float e1 = v1 ? expf(s1 - m) : 0.f;
    float Z  = block_reduce_sum(e0 + e1);

    float w0 = fminf(fmaxf(e0 / Z, 0.f), 0.1f);
    float w1 = v1 ? fminf(fmaxf(e1 / Z, 0.f), 0.1f) : 0.f;

    for (int it = 0; it < 20; it++) {
        float total  = block_reduce_sum(w0 + w1);
        float excess = total - 1.f;
        bool active  = excess > 1e-6f;
        float sur0 = fmaxf(w0 - 0.1f, 0.f);
        float sur1 = fmaxf(w1 - 0.1f, 0.f);
        float totsur = block_reduce_sum(sur0 + sur1);
        float u0, u1;
        if (totsur > 0.f) {
            float k = excess / fmaxf(totsur, 1e-12f);
            u0 = w0 - sur0 * k;
            u1 = w1 - sur1 * k;
        } else {
            u0 = w0 - excess / (float)NIN;
            u1 = w1 - excess / (float)NIN;
        }
        u0 = fminf(fmaxf(u0, 0.f), 0.1f);
        u1 = fminf(fmaxf(u1, 0.f), 0.1f);
        if (active) { w0 = u0; w1 = u1; }
    }

    out[(long)b * NIN + i0] = w0;
    if (v1) out[(long)b * NIN + i1] = w1;
}

// ---------------------------------------------------------------------------
extern "C" void kernel_launch(void* const* d_in, const int* in_sizes, int n_in,
                              void* d_out, int out_size, void* d_ws, size_t ws_size,
                              hipStream_t stream)
{
    const float* x     = (const float*)d_in[0];
    const float* w_ih0 = (const float*)d_in[1];
    const float* w_hh0 = (const float*)d_in[2];
    const float* b_ih0 = (const float*)d_in[3];
    const float* b_hh0 = (const float*)d_in[4];
    const float* w_ih1 = (const float*)d_in[5];
    const float* w_hh1 = (const float*)d_in[6];
    const float* b_ih1 = (const float*)d_in[7];
    const float* b_hh1 = (const float*)d_in[8];
    const float* w1    = (const float*)d_in[9];
    const float* b1    = (const float*)d_in[10];
    const float* ln_g  = (const float*)d_in[11];
    const float* ln_b  = (const float*)d_in[12];
    const float* w2    = (const float*)d_in[13];
    const float* b2    = (const float*)d_in[14];
    float* out = (float*)d_out;

    // ---- plane-path workspace sizing ----
    const size_t fixedB = 88006656UL /*u16 planes*/ + 3121152UL /*zb+sc*/;
    const size_t perTcB = 11010048UL;   // gxc + xs + h0seq per Tc unit
    int Tc = 0;
    const int cands[6] = {32, 16, 8, 4, 2, 1};
    for (int ci = 0; ci < 6; ci++)
        if (fixedB + (size_t)cands[ci] * perTcB <= ws_size) { Tc = cands[ci]; break; }

    dim3 blk(256);

    if (Tc > 0) {
        // ================= plane path =================
        char* base = (char*)d_ws;
        u16* whh0p = (u16*)base; base += 9437184UL * 2;
        u16* whh1p = (u16*)base; base += 9437184UL * 2;
        u16* wih1p = (u16*)base; base += 9437184UL * 2;
        u16* wih0p = (u16*)base; base += 4718592UL * 2;
        u16* w1p   = (u16*)base; base += 3145728UL * 2;
        u16* w2p   = (u16*)base; base += 1536000UL * 2;
        u16* h1ap  = (u16*)base; base += 1572864UL * 2;
        u16* h1bp  = (u16*)base; base += 1572864UL * 2;
        u16* hzp   = (u16*)base; base += 1572864UL * 2;
        u16* zplp  = (u16*)base; base += 1572864UL * 2;
        float* zb  = (float*)base; base += 524288UL * 4;
        float* sc  = (float*)base; base += 256000UL * 4;
        float* gxc = (float*)base; base += (size_t)Tc * 512 * G3 * 4;
        u16* xsp   = (u16*)base;   base += (size_t)3 * Tc * 512 * NINP * 2;
        u16* h0sp  = (u16*)base;

        // pre-split weights into bf16 h/m/l planes (once per call)
        split_mat<<<3072, blk, 0, stream>>>(w_hh0, whh0p, 3072, 1024, 1024);
        split_mat<<<3072, blk, 0, stream>>>(w_hh1, whh1p, 3072, 1024, 1024);
        split_mat<<<3072, blk, 0, stream>>>(w_ih1, wih1p, 3072, 1024, 1024);
        split_mat<<<1536, blk, 0, stream>>>(w_ih0, wih0p, 3072, 500, NINP);
        split_mat<<<1024, blk, 0, stream>>>(w1, w1p, 1024, 1024, 1024);
        split_mat<<<500,  blk, 0, stream>>>(w2, w2p, 500, 1024, 1024);
        hipMemsetAsync(hzp, 0, 1572864UL * 2, stream);

        int nch = SEQ_T / Tc;
        for (int c = 0; c < nch; c++) {
            int t0 = c * Tc;
            split_x<<<Tc * 256, blk, 0, stream>>>(x, xsp, t0, Tc);
            dim3 gBig((Tc * 512) / 64, 48);
            gemm_ps<<<gBig, blk, 0, stream>>>(xsp, (long)Tc * 512 * NINP, NINP,
                                              wih0p, 3072L * NINP, NINP,
                                              b_ih0, gxc, G3, Tc * 512, G3, NINP);
            for (int tt = 0; tt < Tc; tt++) {
                const u16* prev; long pps;
                if (tt > 0)     { prev = h0sp + (long)(tt - 1) * HPS1; pps = (long)Tc * HPS1; }
                else if (c > 0) { prev = h0sp + (long)(Tc - 1) * HPS1; pps = (long)Tc * HPS1; }
                else            { prev = hzp; pps = (long)HPS1; }
                gru_fused<<<dim3(8, 32), blk, 0, stream>>>(prev, pps, whh0p, b_hh0,
                    gxc + (long)tt * 512 * G3, h0sp + (long)tt * HPS1, (long)Tc * HPS1);
            }
            gemm_ps<<<gBig, blk, 0, stream>>>(h0sp, (long)Tc * HPS1, HID,
                                              wih1p, 3072L * HID, HID,
                                              b_ih1, gxc, G3, Tc * 512, G3, HID);
            for (int tt = 0; tt < Tc; tt++) {
                int t = t0 + tt;
                u16* next = (t & 1) ? h1bp : h1ap;
                const u16* prev = (t == 0) ? hzp : ((t & 1) ? h1ap : h1bp);
                gru_fused<<<dim3(8, 32), blk, 0, stream>>>(prev, (long)HPS1, whh1p, b_hh1,
                    gxc + (long)tt * 512 * G3, next, (long)HPS1);
            }
        }
        // hT = h1bp (t=127 odd)
        gemm_ps<<<dim3(8, 16), blk, 0, stream>>>(h1bp, (long)HPS1, HID,
                                                 w1p, 1024L * 1024, HID,
                                                 b1, zb, HID, 512, HID, HID);
        ln_silu<<<dim3(512), blk, 0, stream>>>(zb, ln_g, ln_b);
        split_mat<<<512, blk, 0, stream>>>(zb, zplp, 512, 1024, 1024);
        gemm_ps<<<dim3(8, 8), blk, 0, stream>>>(zplp, (long)HPS1, HID,
                                                w2p, 500L * 1024, HID,
                                                b2, sc, NIN, 512, NIN, HID);
        head_softmax_rebalance<<<dim3(512), blk, 0, stream>>>(sc, out);
    } else {
        // ================= legacy (round-3) fallback =================
        float* ws = (float*)d_ws;
        float* h1a   = ws; ws += (size_t)BATCH * HID;
        float* h1b   = ws; ws += (size_t)BATCH * HID;
        float* hzero = ws; ws += (size_t)BATCH * HID;
        float* gh    = ws; ws += (size_t)BATCH * G3;
        float* zb    = ws; ws += (size_t)BATCH * HID;
        float* sc    = ws; ws += (size_t)BATCH * NIN;
        size_t fixed_floats = (size_t)(ws - (float*)d_ws);
        int Tc2 = 1;
        const int cands2[6] = {32, 16, 8, 4, 2, 1};
        for (int ci = 0; ci < 6; ci++) {
            size_t need = fixed_floats + (size_t)cands2[ci] * BATCH * (G3 + HID);
            if (need * sizeof(float) <= ws_size) { Tc2 = cands2[ci]; break; }
        }
        float* gxc   = ws; ws += (size_t)Tc2 * BATCH * G3;
        float* h0seq = ws;

        hipMemsetAsync(hzero, 0, (size_t)BATCH * HID * sizeof(float), stream);
        dim3 gHH(BATCH / 64, G3 / 64);
        dim3 gUpd((BATCH * HID / 4) / 256);
        const long sBH = (long)BATCH * HID;
        const long sBG = (long)BATCH * G3;

        for (int c = 0; c < SEQ_T / Tc2; c++) {
            int t0 = c * Tc2;
            dim3 gBig((Tc2 * BATCH) / 64, G3 / 64);
            gemm_b6<<<gBig, blk, 0, stream>>>(x + (long)t0 * NIN, (long)NIN, (long)SEQ_T * NIN,
                                              w_ih0, b_ih0, gxc, Tc2 * BATCH, G3, NIN);
            for (int tt = 0; tt < Tc2; tt++) {
                const float* prev0 = (tt > 0) ? (h0seq + (long)(tt - 1) * sBH)
                                   : (c > 0)  ? (h0seq + (long)(Tc2 - 1) * sBH)
                                              : hzero;
                gemm_b6<<<gHH, blk, 0, stream>>>(prev0, 0L, (long)HID, w_hh0, b_hh0, gh, BATCH, G3, HID);
                gru_update4<<<gUpd, blk, 0, stream>>>((const float4*)(gxc + (long)tt * sBG), (const float4*)gh,
                                                      (const float4*)prev0, (float4*)(h0seq + (long)tt * sBH));
            }
            gemm_b6<<<gBig, blk, 0, stream>>>(h0seq, sBH, (long)HID,
                                              w_ih1, b_ih1, gxc, Tc2 * BATCH, G3, HID);
            for (int tt = 0; tt < Tc2; tt++) {
                int t = t0 + tt;
                float* next1 = (t % 2 == 0) ? h1a : h1b;
                const float* prev1 = (t == 0) ? hzero : ((t % 2 == 0) ? h1b : h1a);
                gemm_b6<<<gHH, blk, 0, stream>>>(prev1, 0L, (long)HID, w_hh1, b_hh1, gh, BATCH, G3, HID);
                gru_update4<<<gUpd, blk, 0, stream>>>((const float4*)(gxc + (long)tt * sBG), (const float4*)gh,
                                                      (const float4*)prev1, (float4*)next1);
            }
        }
        const float* hT = h1b;
        dim3 gZ(BATCH / 64, HID / 64);
        gemm_b6<<<gZ, blk, 0, stream>>>(hT, 0L, (long)HID, w1, b1, zb, BATCH, HID, HID);
        ln_silu<<<dim3(BATCH), blk, 0, stream>>>(zb, ln_g, ln_b);
        dim3 gS(BATCH / 64, (NIN + 63) / 64);
        gemm_b6<<<gS, blk, 0, stream>>>(zb, 0L, (long)HID, w2, b2, sc, BATCH, NIN, HID);
        head_softmax_rebalance<<<dim3(BATCH), blk, 0, stream>>>(sc, out);
    }
}